// Round 10
// baseline (575.043 us; speedup 1.0000x reference)
//
#include <hip/hip_runtime.h>
#include <math.h>

#define N_NODES 50000
#define N_EDGES 800000

// fp32 = a0+a1+a2 (3 bf16 terms). 6 MFMA term-pairs per product -> fp32-class
// numerics on the bf16 matrix core (~2^-25 trunc-split; needed for the binary
// `actions` output).
typedef __attribute__((ext_vector_type(8))) short short8_t;   // bf16x8 (4 VGPR)
typedef __attribute__((ext_vector_type(4))) float float4_t;   // fp32x4 acc

union U8 { short8_t v; unsigned short u[8]; };

__device__ __forceinline__ unsigned short bf16_rn(float f) {
    unsigned u = __float_as_uint(f);
    u += 0x7fffu + ((u >> 16) & 1u);
    return (unsigned short)(u >> 16);
}
__device__ __forceinline__ float bf2f(unsigned short h) {
    return __uint_as_float((unsigned)h << 16);
}
// round-to-nearest split (prep only)
__device__ __forceinline__ void split3(float f, unsigned short& s0,
                                       unsigned short& s1, unsigned short& s2) {
    s0 = bf16_rn(f);  float r = f - bf2f(s0);
    s1 = bf16_rn(r);  r -= bf2f(s1);
    s2 = bf16_rn(r);
}
// truncation split (hot kernels): trunc/sub exact, only s2 rounds.
__device__ __forceinline__ void split3t(float f, unsigned short& s0,
                                        unsigned short& s1, unsigned short& s2) {
    unsigned u = __float_as_uint(f);
    s0 = (unsigned short)(u >> 16);
    float r = f - bf2f(s0);            // exact
    unsigned v = __float_as_uint(r);
    s1 = (unsigned short)(v >> 16);
    float r2 = r - bf2f(s1);           // exact
    s2 = bf16_rn(r2);
}

// ---------------------------------------------------------------------------
// ws layout (bytes):
//   BTn0/1/2 [256][128] bf16 : rows 0..127 = F1^T (P), 128..255 = F2^T (Q,x)
//   BTg0/1/2 [128][128] bf16 : F3^T (Q,g)
//   BTw0/1/2 [192][128] bf16 : [vp_W1 | pol_W1]^T
//   cb[128] folded bias (into P), b1c[192], W2c[192], flags[16]
//   P[50000*128] = x@F1 + cb ; Q[50000*128] = x@F2 + g@F3
// ---------------------------------------------------------------------------

__global__ __launch_bounds__(256) void prep_kernel(
    const float* __restrict__ node_W, const float* __restrict__ node_b,
    const float* __restrict__ nbr_W,  const float* __restrict__ nbr_b,
    const float* __restrict__ gud_W,  const float* __restrict__ gud_b,
    const float* __restrict__ enc_W,  const float* __restrict__ enc_b,
    const float* __restrict__ vp_W1,  const float* __restrict__ vp_b1,
    const float* __restrict__ vp_W2,  const float* __restrict__ pol_W1,
    const float* __restrict__ pol_b1, const float* __restrict__ pol_W2,
    unsigned short* __restrict__ BTn0, unsigned short* __restrict__ BTn1,
    unsigned short* __restrict__ BTn2,
    unsigned short* __restrict__ BTg0, unsigned short* __restrict__ BTg1,
    unsigned short* __restrict__ BTg2,
    unsigned short* __restrict__ BTw0, unsigned short* __restrict__ BTw1,
    unsigned short* __restrict__ BTw2,
    float* __restrict__ cb, float* __restrict__ b1c, float* __restrict__ W2c,
    int* __restrict__ flags)
{
    const int k = blockIdx.x;   // input channel 0..127
    const int j = threadIdx.x;  // output channel
    if (j < 128) {
        float a = 0.f, b = 0.f;
        #pragma unroll 4
        for (int m = 0; m < 128; ++m) {
            a = fmaf(node_W[k * 128 + m], enc_W[m * 128 + j], a);
            b = fmaf(gud_W [k * 128 + m], enc_W[(256 + m) * 128 + j], b);
        }
        size_t i1 = (size_t)j * 128 + k;          // B^T[n=j][k]
        split3(a, BTn0[i1], BTn1[i1], BTn2[i1]);
        split3(b, BTg0[i1], BTg1[i1], BTg2[i1]);
    } else {
        const int n = j - 128;
        float a = 0.f;
        #pragma unroll 4
        for (int m = 0; m < 128; ++m)
            a = fmaf(nbr_W[k * 128 + m], enc_W[(128 + m) * 128 + n], a);
        size_t i2 = (size_t)(128 + n) * 128 + k;  // B^T[n=128+n][k]
        split3(a, BTn0[i2], BTn1[i2], BTn2[i2]);
    }
    if (j < 192) {
        float wv = (j < 64) ? vp_W1[k * 64 + j] : pol_W1[k * 128 + (j - 64)];
        size_t iw = (size_t)j * 128 + k;
        split3(wv, BTw0[iw], BTw1[iw], BTw2[iw]);
    }
    if (k == 0) {
        if (j < 128) {
            float cc = enc_b[j];
            for (int m = 0; m < 128; ++m) {
                cc = fmaf(node_b[m], enc_W[m * 128 + j], cc);
                cc = fmaf(nbr_b [m], enc_W[(128 + m) * 128 + j], cc);
                cc = fmaf(gud_b [m], enc_W[(256 + m) * 128 + j], cc);
            }
            cb[j] = cc;
        }
        if (j < 192) {
            b1c[j] = (j < 64) ? vp_b1[j] : pol_b1[j - 64];
            W2c[j] = (j < 64) ? vp_W2[j] : pol_W2[j - 64];
        }
        // --- runtime C/D orientation probe (wave 0), verified rounds 5/6/9 ---
        if (j < 64) {
            const int l = j, li = l & 15, lq = l >> 4;
            U8 A, B;
            #pragma unroll
            for (int u = 0; u < 8; ++u) { A.u[u] = 0; B.u[u] = 0; }
            if (lq == 0) {
                A.u[0] = bf16_rn((float)(li + 1));
                A.u[1] = bf16_rn(1.0f);
                B.u[0] = bf16_rn(1.0f);
                B.u[1] = bf16_rn((float)(100 * (li + 1)));
            }
            float4_t d = (float4_t){0.f, 0.f, 0.f, 0.f};
            d = __builtin_amdgcn_mfma_f32_16x16x32_bf16(A.v, B.v, d, 0, 0, 0);
            if (l == 17) {
                flags[0] = (fabsf(d[2] - 702.f) < 1.0f) ? 1 : 0;
            }
        }
    }
}

// ---------------------------------------------------------------------------
// node_kernel: 64 nodes/block; x/g split once per block into LDS; striped
// N-tile ownership (wave w owns tiles {w, w+4, w+8, w+12}); 2-barrier per kc
// (single-buffer); gather prefetch under MFMA. (R6/R9 verbatim — passed 2x.)
// ---------------------------------------------------------------------------
__global__ __launch_bounds__(256, 3) void node_kernel(
    const float* __restrict__ x, const float* __restrict__ g,
    const unsigned short* __restrict__ BTn0, const unsigned short* __restrict__ BTn1,
    const unsigned short* __restrict__ BTn2,
    const unsigned short* __restrict__ BTg0, const unsigned short* __restrict__ BTg1,
    const unsigned short* __restrict__ BTg2,
    const float* __restrict__ cb, const int* __restrict__ flags,
    float* __restrict__ P, float* __restrict__ Q)
{
    __shared__ unsigned short a0s[4 * 64 * 8];   // [k-sub][node][8]
    __shared__ unsigned short a1s[4 * 64 * 8];
    __shared__ unsigned short a2s[4 * 64 * 8];
    const int t = threadIdx.x;
    const int w = t >> 6, lane = t & 63;
    const int i16 = lane & 15, q = lane >> 4;
    const int base = blockIdx.x * 64;
    const int swap = flags[0];
    const int el = t >> 2, hh = t & 3;   // 4 threads/node, 8 ch each
    int nodeL = base + el; if (nodeL > N_NODES - 1) nodeL = N_NODES - 1;
    const float* xrow = x + (size_t)nodeL * 128 + hh * 8;
    const float* grow = g + (size_t)nodeL * 128 + hh * 8;

    float4_t acc[4][4];
    #pragma unroll
    for (int mt = 0; mt < 4; ++mt)
        #pragma unroll
        for (int nt = 0; nt < 4; ++nt) acc[mt][nt] = (float4_t){0.f, 0.f, 0.f, 0.f};

    float4 pv0 = *(const float4*)(xrow);
    float4 pv1 = *(const float4*)(xrow + 4);

    for (int kc = 0; kc < 8; ++kc) {
        U8 s0, s1, s2;
        {
            float e[8] = {pv0.x, pv0.y, pv0.z, pv0.w, pv1.x, pv1.y, pv1.z, pv1.w};
            #pragma unroll
            for (int u = 0; u < 8; ++u) split3t(e[u], s0.u[u], s1.u[u], s2.u[u]);
        }
        __syncthreads();   // prior kc's A-frag reads done
        {
            size_t off = ((size_t)hh * 64 + el) * 8;
            *(short8_t*)(a0s + off) = s0.v;
            *(short8_t*)(a1s + off) = s1.v;
            *(short8_t*)(a2s + off) = s2.v;
        }
        __syncthreads();
        if (kc < 7) {   // prefetch next chunk under the MFMA phase
            const float* nsrc = (kc + 1 < 4) ? (xrow + (kc + 1) * 32)
                                             : (grow + (kc + 1 - 4) * 32);
            pv0 = *(const float4*)(nsrc);
            pv1 = *(const float4*)(nsrc + 4);
        }
        if (kc < 4) {
            short8_t b0[4], b1v[4], b2v[4];
            #pragma unroll
            for (int ntl = 0; ntl < 4; ++ntl) {
                int ntg = w + ntl * 4;
                size_t roff = ((size_t)(ntg * 16 + i16)) * 128 + kc * 32 + q * 8;
                b0[ntl]  = *(const short8_t*)(BTn0 + roff);
                b1v[ntl] = *(const short8_t*)(BTn1 + roff);
                b2v[ntl] = *(const short8_t*)(BTn2 + roff);
            }
            #pragma unroll
            for (int mt = 0; mt < 4; ++mt) {
                size_t aoff = ((size_t)q * 64 + mt * 16 + i16) * 8;
                short8_t a0 = *(const short8_t*)(a0s + aoff);
                short8_t a1 = *(const short8_t*)(a1s + aoff);
                short8_t a2 = *(const short8_t*)(a2s + aoff);
                #pragma unroll
                for (int ntl = 0; ntl < 4; ++ntl) {
                    float4_t c = acc[mt][ntl];
                    c = __builtin_amdgcn_mfma_f32_16x16x32_bf16(a0, b0[ntl],  c, 0, 0, 0);
                    c = __builtin_amdgcn_mfma_f32_16x16x32_bf16(a0, b1v[ntl], c, 0, 0, 0);
                    c = __builtin_amdgcn_mfma_f32_16x16x32_bf16(a1, b0[ntl],  c, 0, 0, 0);
                    c = __builtin_amdgcn_mfma_f32_16x16x32_bf16(a0, b2v[ntl], c, 0, 0, 0);
                    c = __builtin_amdgcn_mfma_f32_16x16x32_bf16(a1, b1v[ntl], c, 0, 0, 0);
                    c = __builtin_amdgcn_mfma_f32_16x16x32_bf16(a2, b0[ntl],  c, 0, 0, 0);
                    acc[mt][ntl] = c;
                }
            }
        } else {
            short8_t b0[2], b1v[2], b2v[2];
            #pragma unroll
            for (int ntl = 0; ntl < 2; ++ntl) {
                int ntg = w + (ntl + 2) * 4;   // Q tiles w+8, w+12
                size_t roff = ((size_t)((ntg - 8) * 16 + i16)) * 128 + (kc - 4) * 32 + q * 8;
                b0[ntl]  = *(const short8_t*)(BTg0 + roff);
                b1v[ntl] = *(const short8_t*)(BTg1 + roff);
                b2v[ntl] = *(const short8_t*)(BTg2 + roff);
            }
            #pragma unroll
            for (int mt = 0; mt < 4; ++mt) {
                size_t aoff = ((size_t)q * 64 + mt * 16 + i16) * 8;
                short8_t a0 = *(const short8_t*)(a0s + aoff);
                short8_t a1 = *(const short8_t*)(a1s + aoff);
                short8_t a2 = *(const short8_t*)(a2s + aoff);
                #pragma unroll
                for (int ntl = 0; ntl < 2; ++ntl) {
                    float4_t c = acc[mt][ntl + 2];
                    c = __builtin_amdgcn_mfma_f32_16x16x32_bf16(a0, b0[ntl],  c, 0, 0, 0);
                    c = __builtin_amdgcn_mfma_f32_16x16x32_bf16(a0, b1v[ntl], c, 0, 0, 0);
                    c = __builtin_amdgcn_mfma_f32_16x16x32_bf16(a1, b0[ntl],  c, 0, 0, 0);
                    c = __builtin_amdgcn_mfma_f32_16x16x32_bf16(a0, b2v[ntl], c, 0, 0, 0);
                    c = __builtin_amdgcn_mfma_f32_16x16x32_bf16(a1, b1v[ntl], c, 0, 0, 0);
                    c = __builtin_amdgcn_mfma_f32_16x16x32_bf16(a2, b0[ntl],  c, 0, 0, 0);
                    acc[mt][ntl + 2] = c;
                }
            }
        }
    }

    if (!swap) {
        #pragma unroll
        for (int mt = 0; mt < 4; ++mt)
            #pragma unroll
            for (int ntl = 0; ntl < 4; ++ntl) {
                int ntg = w + ntl * 4;
                int chan = ntg * 16 + i16;
                bool isP = (ntg < 8);
                float bias = isP ? cb[chan] : 0.f;
                #pragma unroll
                for (int r = 0; r < 4; ++r) {
                    int node = base + mt * 16 + q * 4 + r;
                    if (node < N_NODES) {
                        if (isP) P[(size_t)node * 128 + chan] = acc[mt][ntl][r] + bias;
                        else     Q[(size_t)node * 128 + (chan - 128)] = acc[mt][ntl][r];
                    }
                }
            }
    } else {
        #pragma unroll
        for (int mt = 0; mt < 4; ++mt) {
            int node = base + mt * 16 + i16;
            if (node < N_NODES) {
                #pragma unroll
                for (int ntl = 0; ntl < 4; ++ntl) {
                    int ntg = w + ntl * 4;
                    int chanb = ntg * 16 + q * 4;
                    bool isP = (ntg < 8);
                    float4 vv;
                    vv.x = acc[mt][ntl][0] + (isP ? cb[chanb + 0] : 0.f);
                    vv.y = acc[mt][ntl][1] + (isP ? cb[chanb + 1] : 0.f);
                    vv.z = acc[mt][ntl][2] + (isP ? cb[chanb + 2] : 0.f);
                    vv.w = acc[mt][ntl][3] + (isP ? cb[chanb + 3] : 0.f);
                    if (isP) *(float4*)(P + (size_t)node * 128 + chanb) = vv;
                    else     *(float4*)(Q + (size_t)node * 128 + chanb - 128) = vv;
                }
            }
        }
    }
}

// ---------------------------------------------------------------------------
// edge_kernel v2: 64 edges/block, acc[4][3] = 48 VGPRs (R9 lesson: hint N
// shrinks the VGPR budget; 96-reg acc spills at hint>=3. Halve the acc).
// Full K=128 enc staged to LDS once (48 KB), ONE barrier per block, then an
// uninterrupted 288-MFMA run per wave. All 16 gather float4s issued up-front.
// ntl-outer MFMA loop keeps B-frags at 9 live regs. 800000 = 12500*64.
// ---------------------------------------------------------------------------
__global__ __launch_bounds__(256, 3) void edge_kernel(
    const int* __restrict__ ei,
    const float* __restrict__ P, const float* __restrict__ Q,
    const unsigned short* __restrict__ BTw0, const unsigned short* __restrict__ BTw1,
    const unsigned short* __restrict__ BTw2,
    const float* __restrict__ b1c, const float* __restrict__ W2c,
    const float* __restrict__ vp_b2, const float* __restrict__ pol_b2,
    const int* __restrict__ flags,
    float* __restrict__ out)
{
    __shared__ unsigned short enc0[16 * 64 * 8];   // [k-sub 0..15][edge][8] = 16 KB
    __shared__ unsigned short enc1[16 * 64 * 8];
    __shared__ unsigned short enc2[16 * 64 * 8];
    __shared__ float vpart[256], ppart[256];

    const int t = threadIdx.x;
    const int w = t >> 6, lane = t & 63;
    const int i16 = lane & 15, q = lane >> 4;
    const int e0 = blockIdx.x * 64;
    const int ntg0 = w * 3;
    const int el = t >> 2, hh = t & 3;   // 4 threads/edge, 32 ch each
    const int swap = flags[0];

    const int rowI = ei[e0 + el];
    const int colI = ei[N_EDGES + e0 + el];
    const float* Pp = P + (size_t)rowI * 128 + hh * 32;
    const float* Qp = Q + (size_t)colI * 128 + hh * 32;

    // stage: all 16 gathers in flight, relu+3-split, store to LDS
    {
        float4 pv[8], qv[8];
        #pragma unroll
        for (int i = 0; i < 8; ++i) {
            pv[i] = *(const float4*)(Pp + i * 4);
            qv[i] = *(const float4*)(Qp + i * 4);
        }
        #pragma unroll
        for (int j = 0; j < 4; ++j) {
            float4 pa = pv[2 * j], pb = pv[2 * j + 1];
            float4 qa = qv[2 * j], qb = qv[2 * j + 1];
            float ev[8] = {
                fmaxf(pa.x + qa.x, 0.f), fmaxf(pa.y + qa.y, 0.f),
                fmaxf(pa.z + qa.z, 0.f), fmaxf(pa.w + qa.w, 0.f),
                fmaxf(pb.x + qb.x, 0.f), fmaxf(pb.y + qb.y, 0.f),
                fmaxf(pb.z + qb.z, 0.f), fmaxf(pb.w + qb.w, 0.f)};
            U8 s0, s1, s2;
            #pragma unroll
            for (int u = 0; u < 8; ++u) split3t(ev[u], s0.u[u], s1.u[u], s2.u[u]);
            size_t off = ((size_t)(hh * 4 + j) * 64 + el) * 8;
            *(short8_t*)(enc0 + off) = s0.v;
            *(short8_t*)(enc1 + off) = s1.v;
            *(short8_t*)(enc2 + off) = s2.v;
        }
    }
    __syncthreads();   // the only barrier before the epilogue

    float4_t acc[4][3];
    #pragma unroll
    for (int mt = 0; mt < 4; ++mt)
        #pragma unroll
        for (int nt = 0; nt < 3; ++nt) acc[mt][nt] = (float4_t){0.f, 0.f, 0.f, 0.f};

    #pragma unroll
    for (int kc = 0; kc < 4; ++kc) {
        #pragma unroll
        for (int ntl = 0; ntl < 3; ++ntl) {
            size_t roff = ((size_t)((ntg0 + ntl) * 16 + i16)) * 128 + kc * 32 + q * 8;
            short8_t b0 = *(const short8_t*)(BTw0 + roff);
            short8_t b1 = *(const short8_t*)(BTw1 + roff);
            short8_t b2 = *(const short8_t*)(BTw2 + roff);
            #pragma unroll
            for (int mt = 0; mt < 4; ++mt) {
                size_t aoff = ((size_t)(kc * 4 + q) * 64 + mt * 16 + i16) * 8;
                short8_t a0 = *(const short8_t*)(enc0 + aoff);
                short8_t a1 = *(const short8_t*)(enc1 + aoff);
                short8_t a2 = *(const short8_t*)(enc2 + aoff);
                float4_t c = acc[mt][ntl];
                c = __builtin_amdgcn_mfma_f32_16x16x32_bf16(a0, b0, c, 0, 0, 0);
                c = __builtin_amdgcn_mfma_f32_16x16x32_bf16(a0, b1, c, 0, 0, 0);
                c = __builtin_amdgcn_mfma_f32_16x16x32_bf16(a1, b0, c, 0, 0, 0);
                c = __builtin_amdgcn_mfma_f32_16x16x32_bf16(a0, b2, c, 0, 0, 0);
                c = __builtin_amdgcn_mfma_f32_16x16x32_bf16(a1, b1, c, 0, 0, 0);
                c = __builtin_amdgcn_mfma_f32_16x16x32_bf16(a2, b0, c, 0, 0, 0);
                acc[mt][ntl] = c;
            }
        }
    }

    // epilogue: bias+relu+W2, reduce, combine waves via LDS (dual-path)
    if (!swap) {
        #pragma unroll
        for (int mt = 0; mt < 4; ++mt) {
            float vs[4] = {0.f, 0.f, 0.f, 0.f}, ps[4] = {0.f, 0.f, 0.f, 0.f};
            #pragma unroll
            for (int ntl = 0; ntl < 3; ++ntl) {
                int ntg = ntg0 + ntl;
                int n = ntg * 16 + i16;
                float b1s = b1c[n], w2s = W2c[n];
                bool isv = (ntg < 4);
                #pragma unroll
                for (int r = 0; r < 4; ++r) {
                    float hv = fmaxf(acc[mt][ntl][r] + b1s, 0.f) * w2s;
                    if (isv) vs[r] += hv; else ps[r] += hv;
                }
            }
            #pragma unroll
            for (int off = 1; off < 16; off <<= 1)
                #pragma unroll
                for (int r = 0; r < 4; ++r) {
                    vs[r] += __shfl_xor(vs[r], off, 64);
                    ps[r] += __shfl_xor(ps[r], off, 64);
                }
            if (i16 == 0)
                #pragma unroll
                for (int r = 0; r < 4; ++r) {
                    int eidx = mt * 16 + q * 4 + r;
                    vpart[w * 64 + eidx] = vs[r];
                    ppart[w * 64 + eidx] = ps[r];
                }
        }
    } else {
        #pragma unroll
        for (int mt = 0; mt < 4; ++mt) {
            float v = 0.f, p = 0.f;
            #pragma unroll
            for (int ntl = 0; ntl < 3; ++ntl) {
                int ntg = ntg0 + ntl;
                bool isv = (ntg < 4);
                #pragma unroll
                for (int r = 0; r < 4; ++r) {
                    int n = ntg * 16 + q * 4 + r;
                    float hv = fmaxf(acc[mt][ntl][r] + b1c[n], 0.f) * W2c[n];
                    if (isv) v += hv; else p += hv;
                }
            }
            v += __shfl_xor(v, 16, 64); v += __shfl_xor(v, 32, 64);
            p += __shfl_xor(p, 16, 64); p += __shfl_xor(p, 32, 64);
            if (q == 0) {
                int eidx = mt * 16 + i16;
                vpart[w * 64 + eidx] = v;
                ppart[w * 64 + eidx] = p;
            }
        }
    }
    __syncthreads();
    if (t < 64) {
        float v  = vpart[t] + vpart[64 + t] + vpart[128 + t] + vpart[192 + t] + vp_b2[0];
        float pl = ppart[t] + ppart[64 + t] + ppart[128 + t] + ppart[192 + t] + pol_b2[0];
        float prob = 1.0f / (1.0f + expf(-pl));
        int e = e0 + t;
        out[e] = v;
        out[N_EDGES + e] = prob;
        out[2 * N_EDGES + e] = (prob > 0.5f) ? 1.0f : 0.0f;
    }
    if (blockIdx.x == 0 && t == 0) out[3 * N_EDGES] = 0.0f;
}

extern "C" void kernel_launch(void* const* d_in, const int* in_sizes, int n_in,
                              void* d_out, int out_size, void* d_ws, size_t ws_size,
                              hipStream_t stream) {
    const float* x      = (const float*)d_in[0];
    const int*   ei     = (const int*)  d_in[1];
    const float* gf     = (const float*)d_in[2];
    const float* node_W = (const float*)d_in[3];
    const float* node_b = (const float*)d_in[4];
    const float* nbr_W  = (const float*)d_in[5];
    const float* nbr_b  = (const float*)d_in[6];
    const float* gud_W  = (const float*)d_in[7];
    const float* gud_b  = (const float*)d_in[8];
    const float* enc_W  = (const float*)d_in[9];
    const float* enc_b  = (const float*)d_in[10];
    const float* vp_W1  = (const float*)d_in[11];
    const float* vp_b1  = (const float*)d_in[12];
    const float* vp_W2  = (const float*)d_in[13];
    const float* vp_b2  = (const float*)d_in[14];
    const float* pol_W1 = (const float*)d_in[15];
    const float* pol_b1 = (const float*)d_in[16];
    const float* pol_W2 = (const float*)d_in[17];
    const float* pol_b2 = (const float*)d_in[18];
    float* out = (float*)d_out;

    unsigned char* wsb = (unsigned char*)d_ws;
    unsigned short* BTn0 = (unsigned short*)(wsb + 0);
    unsigned short* BTn1 = (unsigned short*)(wsb + 65536);
    unsigned short* BTn2 = (unsigned short*)(wsb + 131072);
    unsigned short* BTg0 = (unsigned short*)(wsb + 196608);
    unsigned short* BTg1 = (unsigned short*)(wsb + 229376);
    unsigned short* BTg2 = (unsigned short*)(wsb + 262144);
    unsigned short* BTw0 = (unsigned short*)(wsb + 294912);
    unsigned short* BTw1 = (unsigned short*)(wsb + 344064);
    unsigned short* BTw2 = (unsigned short*)(wsb + 393216);
    float* cb   = (float*)(wsb + 442368);
    float* b1c  = (float*)(wsb + 442880);
    float* W2c  = (float*)(wsb + 443648);
    int*   flags= (int*)  (wsb + 444416);
    float* Pd   = (float*)(wsb + 444480);
    float* Qd   = Pd + (size_t)N_NODES * 128;

    prep_kernel<<<dim3(128), dim3(256), 0, stream>>>(
        node_W, node_b, nbr_W, nbr_b, gud_W, gud_b, enc_W, enc_b,
        vp_W1, vp_b1, vp_W2, pol_W1, pol_b1, pol_W2,
        BTn0, BTn1, BTn2, BTg0, BTg1, BTg2, BTw0, BTw1, BTw2,
        cb, b1c, W2c, flags);

    node_kernel<<<dim3((N_NODES + 63) / 64), dim3(256), 0, stream>>>(
        x, gf, BTn0, BTn1, BTn2, BTg0, BTg1, BTg2, cb, flags, Pd, Qd);

    edge_kernel<<<dim3(N_EDGES / 64), dim3(256), 0, stream>>>(
        ei, Pd, Qd, BTw0, BTw1, BTw2, b1c, W2c, vp_b2, pol_b2, flags, out);
}

// Round 11
// 524.669 us; speedup vs baseline: 1.0960x; 1.0960x over previous
//
#include <hip/hip_runtime.h>
#include <math.h>

#define N_NODES 50000
#define N_EDGES 800000

// fp32 = a0+a1+a2 (3 bf16 terms). 6 MFMA term-pairs per product -> fp32-class
// numerics on the bf16 matrix core (~2^-25 trunc-split; needed for the binary
// `actions` output).
typedef __attribute__((ext_vector_type(8))) short short8_t;   // bf16x8 (4 VGPR)
typedef __attribute__((ext_vector_type(4))) float float4_t;   // fp32x4 acc

union U8 { short8_t v; unsigned short u[8]; };

__device__ __forceinline__ unsigned short bf16_rn(float f) {
    unsigned u = __float_as_uint(f);
    u += 0x7fffu + ((u >> 16) & 1u);
    return (unsigned short)(u >> 16);
}
__device__ __forceinline__ float bf2f(unsigned short h) {
    return __uint_as_float((unsigned)h << 16);
}
// round-to-nearest split (prep only)
__device__ __forceinline__ void split3(float f, unsigned short& s0,
                                       unsigned short& s1, unsigned short& s2) {
    s0 = bf16_rn(f);  float r = f - bf2f(s0);
    s1 = bf16_rn(r);  r -= bf2f(s1);
    s2 = bf16_rn(r);
}
// truncation split (hot kernels): trunc/sub exact, only s2 rounds.
__device__ __forceinline__ void split3t(float f, unsigned short& s0,
                                        unsigned short& s1, unsigned short& s2) {
    unsigned u = __float_as_uint(f);
    s0 = (unsigned short)(u >> 16);
    float r = f - bf2f(s0);            // exact
    unsigned v = __float_as_uint(r);
    s1 = (unsigned short)(v >> 16);
    float r2 = r - bf2f(s1);           // exact
    s2 = bf16_rn(r2);
}

// ---------------------------------------------------------------------------
// ws layout (bytes):
//   BTn0/1/2 [256][128] bf16 : rows 0..127 = F1^T (P), 128..255 = F2^T (Q,x)
//   BTg0/1/2 [128][128] bf16 : F3^T (Q,g)
//   BTw0/1/2 [192][128] bf16 : [vp_W1 | pol_W1]^T
//   cb[128] folded bias (into P), b1c[192], W2c[192], flags[16]
//   P[50000*128] = x@F1 + cb ; Q[50000*128] = x@F2 + g@F3
// ---------------------------------------------------------------------------

__global__ __launch_bounds__(256) void prep_kernel(
    const float* __restrict__ node_W, const float* __restrict__ node_b,
    const float* __restrict__ nbr_W,  const float* __restrict__ nbr_b,
    const float* __restrict__ gud_W,  const float* __restrict__ gud_b,
    const float* __restrict__ enc_W,  const float* __restrict__ enc_b,
    const float* __restrict__ vp_W1,  const float* __restrict__ vp_b1,
    const float* __restrict__ vp_W2,  const float* __restrict__ pol_W1,
    const float* __restrict__ pol_b1, const float* __restrict__ pol_W2,
    unsigned short* __restrict__ BTn0, unsigned short* __restrict__ BTn1,
    unsigned short* __restrict__ BTn2,
    unsigned short* __restrict__ BTg0, unsigned short* __restrict__ BTg1,
    unsigned short* __restrict__ BTg2,
    unsigned short* __restrict__ BTw0, unsigned short* __restrict__ BTw1,
    unsigned short* __restrict__ BTw2,
    float* __restrict__ cb, float* __restrict__ b1c, float* __restrict__ W2c,
    int* __restrict__ flags)
{
    const int k = blockIdx.x;   // input channel 0..127
    const int j = threadIdx.x;  // output channel
    if (j < 128) {
        float a = 0.f, b = 0.f;
        #pragma unroll 4
        for (int m = 0; m < 128; ++m) {
            a = fmaf(node_W[k * 128 + m], enc_W[m * 128 + j], a);
            b = fmaf(gud_W [k * 128 + m], enc_W[(256 + m) * 128 + j], b);
        }
        size_t i1 = (size_t)j * 128 + k;          // B^T[n=j][k]
        split3(a, BTn0[i1], BTn1[i1], BTn2[i1]);
        split3(b, BTg0[i1], BTg1[i1], BTg2[i1]);
    } else {
        const int n = j - 128;
        float a = 0.f;
        #pragma unroll 4
        for (int m = 0; m < 128; ++m)
            a = fmaf(nbr_W[k * 128 + m], enc_W[(128 + m) * 128 + n], a);
        size_t i2 = (size_t)(128 + n) * 128 + k;  // B^T[n=128+n][k]
        split3(a, BTn0[i2], BTn1[i2], BTn2[i2]);
    }
    if (j < 192) {
        float wv = (j < 64) ? vp_W1[k * 64 + j] : pol_W1[k * 128 + (j - 64)];
        size_t iw = (size_t)j * 128 + k;
        split3(wv, BTw0[iw], BTw1[iw], BTw2[iw]);
    }
    if (k == 0) {
        if (j < 128) {
            float cc = enc_b[j];
            for (int m = 0; m < 128; ++m) {
                cc = fmaf(node_b[m], enc_W[m * 128 + j], cc);
                cc = fmaf(nbr_b [m], enc_W[(128 + m) * 128 + j], cc);
                cc = fmaf(gud_b [m], enc_W[(256 + m) * 128 + j], cc);
            }
            cb[j] = cc;
        }
        if (j < 192) {
            b1c[j] = (j < 64) ? vp_b1[j] : pol_b1[j - 64];
            W2c[j] = (j < 64) ? vp_W2[j] : pol_W2[j - 64];
        }
        // --- runtime C/D orientation probe (wave 0), verified rounds 5-10 ---
        if (j < 64) {
            const int l = j, li = l & 15, lq = l >> 4;
            U8 A, B;
            #pragma unroll
            for (int u = 0; u < 8; ++u) { A.u[u] = 0; B.u[u] = 0; }
            if (lq == 0) {
                A.u[0] = bf16_rn((float)(li + 1));
                A.u[1] = bf16_rn(1.0f);
                B.u[0] = bf16_rn(1.0f);
                B.u[1] = bf16_rn((float)(100 * (li + 1)));
            }
            float4_t d = (float4_t){0.f, 0.f, 0.f, 0.f};
            d = __builtin_amdgcn_mfma_f32_16x16x32_bf16(A.v, B.v, d, 0, 0, 0);
            if (l == 17) {
                flags[0] = (fabsf(d[2] - 702.f) < 1.0f) ? 1 : 0;
            }
        }
    }
}

// ---------------------------------------------------------------------------
// node_kernel: 64 nodes/block; x/g split once per block into LDS; striped
// N-tile ownership (wave w owns tiles {w, w+4, w+8, w+12}); 2-barrier per kc
// (single-buffer); gather prefetch under MFMA. (R6/R9 verbatim — passed 3x.)
// ---------------------------------------------------------------------------
__global__ __launch_bounds__(256, 3) void node_kernel(
    const float* __restrict__ x, const float* __restrict__ g,
    const unsigned short* __restrict__ BTn0, const unsigned short* __restrict__ BTn1,
    const unsigned short* __restrict__ BTn2,
    const unsigned short* __restrict__ BTg0, const unsigned short* __restrict__ BTg1,
    const unsigned short* __restrict__ BTg2,
    const float* __restrict__ cb, const int* __restrict__ flags,
    float* __restrict__ P, float* __restrict__ Q)
{
    __shared__ unsigned short a0s[4 * 64 * 8];   // [k-sub][node][8]
    __shared__ unsigned short a1s[4 * 64 * 8];
    __shared__ unsigned short a2s[4 * 64 * 8];
    const int t = threadIdx.x;
    const int w = t >> 6, lane = t & 63;
    const int i16 = lane & 15, q = lane >> 4;
    const int base = blockIdx.x * 64;
    const int swap = flags[0];
    const int el = t >> 2, hh = t & 3;   // 4 threads/node, 8 ch each
    int nodeL = base + el; if (nodeL > N_NODES - 1) nodeL = N_NODES - 1;
    const float* xrow = x + (size_t)nodeL * 128 + hh * 8;
    const float* grow = g + (size_t)nodeL * 128 + hh * 8;

    float4_t acc[4][4];
    #pragma unroll
    for (int mt = 0; mt < 4; ++mt)
        #pragma unroll
        for (int nt = 0; nt < 4; ++nt) acc[mt][nt] = (float4_t){0.f, 0.f, 0.f, 0.f};

    float4 pv0 = *(const float4*)(xrow);
    float4 pv1 = *(const float4*)(xrow + 4);

    for (int kc = 0; kc < 8; ++kc) {
        U8 s0, s1, s2;
        {
            float e[8] = {pv0.x, pv0.y, pv0.z, pv0.w, pv1.x, pv1.y, pv1.z, pv1.w};
            #pragma unroll
            for (int u = 0; u < 8; ++u) split3t(e[u], s0.u[u], s1.u[u], s2.u[u]);
        }
        __syncthreads();   // prior kc's A-frag reads done
        {
            size_t off = ((size_t)hh * 64 + el) * 8;
            *(short8_t*)(a0s + off) = s0.v;
            *(short8_t*)(a1s + off) = s1.v;
            *(short8_t*)(a2s + off) = s2.v;
        }
        __syncthreads();
        if (kc < 7) {   // prefetch next chunk under the MFMA phase
            const float* nsrc = (kc + 1 < 4) ? (xrow + (kc + 1) * 32)
                                             : (grow + (kc + 1 - 4) * 32);
            pv0 = *(const float4*)(nsrc);
            pv1 = *(const float4*)(nsrc + 4);
        }
        if (kc < 4) {
            short8_t b0[4], b1v[4], b2v[4];
            #pragma unroll
            for (int ntl = 0; ntl < 4; ++ntl) {
                int ntg = w + ntl * 4;
                size_t roff = ((size_t)(ntg * 16 + i16)) * 128 + kc * 32 + q * 8;
                b0[ntl]  = *(const short8_t*)(BTn0 + roff);
                b1v[ntl] = *(const short8_t*)(BTn1 + roff);
                b2v[ntl] = *(const short8_t*)(BTn2 + roff);
            }
            #pragma unroll
            for (int mt = 0; mt < 4; ++mt) {
                size_t aoff = ((size_t)q * 64 + mt * 16 + i16) * 8;
                short8_t a0 = *(const short8_t*)(a0s + aoff);
                short8_t a1 = *(const short8_t*)(a1s + aoff);
                short8_t a2 = *(const short8_t*)(a2s + aoff);
                #pragma unroll
                for (int ntl = 0; ntl < 4; ++ntl) {
                    float4_t c = acc[mt][ntl];
                    c = __builtin_amdgcn_mfma_f32_16x16x32_bf16(a0, b0[ntl],  c, 0, 0, 0);
                    c = __builtin_amdgcn_mfma_f32_16x16x32_bf16(a0, b1v[ntl], c, 0, 0, 0);
                    c = __builtin_amdgcn_mfma_f32_16x16x32_bf16(a1, b0[ntl],  c, 0, 0, 0);
                    c = __builtin_amdgcn_mfma_f32_16x16x32_bf16(a0, b2v[ntl], c, 0, 0, 0);
                    c = __builtin_amdgcn_mfma_f32_16x16x32_bf16(a1, b1v[ntl], c, 0, 0, 0);
                    c = __builtin_amdgcn_mfma_f32_16x16x32_bf16(a2, b0[ntl],  c, 0, 0, 0);
                    acc[mt][ntl] = c;
                }
            }
        } else {
            short8_t b0[2], b1v[2], b2v[2];
            #pragma unroll
            for (int ntl = 0; ntl < 2; ++ntl) {
                int ntg = w + (ntl + 2) * 4;   // Q tiles w+8, w+12
                size_t roff = ((size_t)((ntg - 8) * 16 + i16)) * 128 + (kc - 4) * 32 + q * 8;
                b0[ntl]  = *(const short8_t*)(BTg0 + roff);
                b1v[ntl] = *(const short8_t*)(BTg1 + roff);
                b2v[ntl] = *(const short8_t*)(BTg2 + roff);
            }
            #pragma unroll
            for (int mt = 0; mt < 4; ++mt) {
                size_t aoff = ((size_t)q * 64 + mt * 16 + i16) * 8;
                short8_t a0 = *(const short8_t*)(a0s + aoff);
                short8_t a1 = *(const short8_t*)(a1s + aoff);
                short8_t a2 = *(const short8_t*)(a2s + aoff);
                #pragma unroll
                for (int ntl = 0; ntl < 2; ++ntl) {
                    float4_t c = acc[mt][ntl + 2];
                    c = __builtin_amdgcn_mfma_f32_16x16x32_bf16(a0, b0[ntl],  c, 0, 0, 0);
                    c = __builtin_amdgcn_mfma_f32_16x16x32_bf16(a0, b1v[ntl], c, 0, 0, 0);
                    c = __builtin_amdgcn_mfma_f32_16x16x32_bf16(a1, b0[ntl],  c, 0, 0, 0);
                    c = __builtin_amdgcn_mfma_f32_16x16x32_bf16(a0, b2v[ntl], c, 0, 0, 0);
                    c = __builtin_amdgcn_mfma_f32_16x16x32_bf16(a1, b1v[ntl], c, 0, 0, 0);
                    c = __builtin_amdgcn_mfma_f32_16x16x32_bf16(a2, b0[ntl],  c, 0, 0, 0);
                    acc[mt][ntl + 2] = c;
                }
            }
        }
    }

    if (!swap) {
        #pragma unroll
        for (int mt = 0; mt < 4; ++mt)
            #pragma unroll
            for (int ntl = 0; ntl < 4; ++ntl) {
                int ntg = w + ntl * 4;
                int chan = ntg * 16 + i16;
                bool isP = (ntg < 8);
                float bias = isP ? cb[chan] : 0.f;
                #pragma unroll
                for (int r = 0; r < 4; ++r) {
                    int node = base + mt * 16 + q * 4 + r;
                    if (node < N_NODES) {
                        if (isP) P[(size_t)node * 128 + chan] = acc[mt][ntl][r] + bias;
                        else     Q[(size_t)node * 128 + (chan - 128)] = acc[mt][ntl][r];
                    }
                }
            }
    } else {
        #pragma unroll
        for (int mt = 0; mt < 4; ++mt) {
            int node = base + mt * 16 + i16;
            if (node < N_NODES) {
                #pragma unroll
                for (int ntl = 0; ntl < 4; ++ntl) {
                    int ntg = w + ntl * 4;
                    int chanb = ntg * 16 + q * 4;
                    bool isP = (ntg < 8);
                    float4 vv;
                    vv.x = acc[mt][ntl][0] + (isP ? cb[chanb + 0] : 0.f);
                    vv.y = acc[mt][ntl][1] + (isP ? cb[chanb + 1] : 0.f);
                    vv.z = acc[mt][ntl][2] + (isP ? cb[chanb + 2] : 0.f);
                    vv.w = acc[mt][ntl][3] + (isP ? cb[chanb + 3] : 0.f);
                    if (isP) *(float4*)(P + (size_t)node * 128 + chanb) = vv;
                    else     *(float4*)(Q + (size_t)node * 128 + chanb - 128) = vv;
                }
            }
        }
    }
}

// ---------------------------------------------------------------------------
// edge_kernel v3: R6 structure (128 edges/block, 8 M-tiles, hint 2 = the
// occupancy sweet spot per R8/R9/R10) + two latency fixes inside hint-2's
// 256-VGPR budget:
//  - B-fragment prefetch: kc+1's 9 B-frags loaded during kc's MFMA phase
//    (B addresses are static; only kc=0's load latency is exposed).
//  - Correctly-sized double-buffered enc LDS [2][4*128*8] -> ONE barrier/kc
//    (R7's version of this had the buffer half-sized; store idx max 4088<4096).
// 800000 = 6250*128.
// ---------------------------------------------------------------------------
__global__ __launch_bounds__(256, 2) void edge_kernel(
    const int* __restrict__ ei,
    const float* __restrict__ P, const float* __restrict__ Q,
    const unsigned short* __restrict__ BTw0, const unsigned short* __restrict__ BTw1,
    const unsigned short* __restrict__ BTw2,
    const float* __restrict__ b1c, const float* __restrict__ W2c,
    const float* __restrict__ vp_b2, const float* __restrict__ pol_b2,
    const int* __restrict__ flags,
    float* __restrict__ out)
{
    __shared__ unsigned short enc0[2][4 * 128 * 8];   // [buf][k-sub][edge][8]
    __shared__ unsigned short enc1[2][4 * 128 * 8];
    __shared__ unsigned short enc2[2][4 * 128 * 8];
    __shared__ float vpart[512], ppart[512];

    const int t = threadIdx.x;
    const int w = t >> 6, lane = t & 63;
    const int i16 = lane & 15, q = lane >> 4;
    const int e0 = blockIdx.x * 128;
    const int ntg0 = w * 3;
    const int el = t >> 1, hh = t & 1;   // 2 threads/edge, 16 ch each
    const int swap = flags[0];

    const int rowI = ei[e0 + el];
    const int colI = ei[N_EDGES + e0 + el];
    const float* Pp = P + (size_t)rowI * 128 + hh * 16;
    const float* Qp = Q + (size_t)colI * 128 + hh * 16;

    float4_t acc[8][3];
    #pragma unroll
    for (int mt = 0; mt < 8; ++mt)
        #pragma unroll
        for (int nt = 0; nt < 3; ++nt) acc[mt][nt] = (float4_t){0.f, 0.f, 0.f, 0.f};

    // kc=0 gathers + kc=0 B-frags up-front (the only exposed loads)
    float4 pv[4], qv[4];
    #pragma unroll
    for (int i = 0; i < 4; ++i) {
        pv[i] = *(const float4*)(Pp + i * 4);
        qv[i] = *(const float4*)(Qp + i * 4);
    }
    short8_t b0[3], b1f[3], b2f[3];
    #pragma unroll
    for (int ntl = 0; ntl < 3; ++ntl) {
        size_t roff = ((size_t)((ntg0 + ntl) * 16 + i16)) * 128 + q * 8;
        b0[ntl]  = *(const short8_t*)(BTw0 + roff);
        b1f[ntl] = *(const short8_t*)(BTw1 + roff);
        b2f[ntl] = *(const short8_t*)(BTw2 + roff);
    }

    #pragma unroll
    for (int kc = 0; kc < 4; ++kc) {
        const int kb = kc & 1;
        // build enc = relu(P+Q) and 3-split (VALU only)
        U8 g0[2], g1[2], g2[2];
        #pragma unroll
        for (int i = 0; i < 4; ++i) {
            float ev[4] = {fmaxf(pv[i].x + qv[i].x, 0.f), fmaxf(pv[i].y + qv[i].y, 0.f),
                           fmaxf(pv[i].z + qv[i].z, 0.f), fmaxf(pv[i].w + qv[i].w, 0.f)};
            #pragma unroll
            for (int u = 0; u < 4; ++u) {
                int idx = i * 4 + u;
                split3t(ev[u], g0[idx >> 3].u[idx & 7], g1[idx >> 3].u[idx & 7],
                        g2[idx >> 3].u[idx & 7]);
            }
        }
        #pragma unroll
        for (int hb = 0; hb < 2; ++hb) {
            size_t off = ((size_t)(2 * hh + hb) * 128 + el) * 8;   // max 4088 < 4096
            *(short8_t*)(enc0[kb] + off) = g0[hb].v;
            *(short8_t*)(enc1[kb] + off) = g1[hb].v;
            *(short8_t*)(enc2[kb] + off) = g2[hb].v;
        }
        __syncthreads();   // single barrier: dbuf makes write-after-read safe
        if (kc < 3) {      // prefetch kc+1 gathers under the MFMA phase
            #pragma unroll
            for (int i = 0; i < 4; ++i) {
                pv[i] = *(const float4*)(Pp + (kc + 1) * 32 + i * 4);
                qv[i] = *(const float4*)(Qp + (kc + 1) * 32 + i * 4);
            }
        }
        // prefetch kc+1 B-frags under the MFMA phase (static addresses)
        short8_t nb0[3], nb1[3], nb2[3];
        if (kc < 3) {
            #pragma unroll
            for (int ntl = 0; ntl < 3; ++ntl) {
                size_t roff = ((size_t)((ntg0 + ntl) * 16 + i16)) * 128 + (kc + 1) * 32 + q * 8;
                nb0[ntl] = *(const short8_t*)(BTw0 + roff);
                nb1[ntl] = *(const short8_t*)(BTw1 + roff);
                nb2[ntl] = *(const short8_t*)(BTw2 + roff);
            }
        }
        #pragma unroll
        for (int mt = 0; mt < 8; ++mt) {
            size_t aoff = ((size_t)q * 128 + mt * 16 + i16) * 8;
            short8_t a0 = *(const short8_t*)(enc0[kb] + aoff);
            short8_t a1 = *(const short8_t*)(enc1[kb] + aoff);
            short8_t a2 = *(const short8_t*)(enc2[kb] + aoff);
            #pragma unroll
            for (int ntl = 0; ntl < 3; ++ntl) {
                float4_t c = acc[mt][ntl];
                c = __builtin_amdgcn_mfma_f32_16x16x32_bf16(a0, b0[ntl],  c, 0, 0, 0);
                c = __builtin_amdgcn_mfma_f32_16x16x32_bf16(a0, b1f[ntl], c, 0, 0, 0);
                c = __builtin_amdgcn_mfma_f32_16x16x32_bf16(a1, b0[ntl],  c, 0, 0, 0);
                c = __builtin_amdgcn_mfma_f32_16x16x32_bf16(a0, b2f[ntl], c, 0, 0, 0);
                c = __builtin_amdgcn_mfma_f32_16x16x32_bf16(a1, b1f[ntl], c, 0, 0, 0);
                c = __builtin_amdgcn_mfma_f32_16x16x32_bf16(a2, b0[ntl],  c, 0, 0, 0);
                acc[mt][ntl] = c;
            }
        }
        if (kc < 3) {   // rotate prefetched B into current
            #pragma unroll
            for (int ntl = 0; ntl < 3; ++ntl) {
                b0[ntl] = nb0[ntl]; b1f[ntl] = nb1[ntl]; b2f[ntl] = nb2[ntl];
            }
        }
    }

    // epilogue: bias+relu+W2, reduce, combine waves via LDS (dual-path)
    if (!swap) {
        #pragma unroll
        for (int mt = 0; mt < 8; ++mt) {
            float vs[4] = {0.f, 0.f, 0.f, 0.f}, ps[4] = {0.f, 0.f, 0.f, 0.f};
            #pragma unroll
            for (int ntl = 0; ntl < 3; ++ntl) {
                int ntg = ntg0 + ntl;
                int n = ntg * 16 + i16;
                float b1s = b1c[n], w2s = W2c[n];
                bool isv = (ntg < 4);
                #pragma unroll
                for (int r = 0; r < 4; ++r) {
                    float hv = fmaxf(acc[mt][ntl][r] + b1s, 0.f) * w2s;
                    if (isv) vs[r] += hv; else ps[r] += hv;
                }
            }
            #pragma unroll
            for (int off = 1; off < 16; off <<= 1)
                #pragma unroll
                for (int r = 0; r < 4; ++r) {
                    vs[r] += __shfl_xor(vs[r], off, 64);
                    ps[r] += __shfl_xor(ps[r], off, 64);
                }
            if (i16 == 0)
                #pragma unroll
                for (int r = 0; r < 4; ++r) {
                    int eidx = mt * 16 + q * 4 + r;
                    vpart[w * 128 + eidx] = vs[r];
                    ppart[w * 128 + eidx] = ps[r];
                }
        }
    } else {
        #pragma unroll
        for (int mt = 0; mt < 8; ++mt) {
            float v = 0.f, p = 0.f;
            #pragma unroll
            for (int ntl = 0; ntl < 3; ++ntl) {
                int ntg = ntg0 + ntl;
                bool isv = (ntg < 4);
                #pragma unroll
                for (int r = 0; r < 4; ++r) {
                    int n = ntg * 16 + q * 4 + r;
                    float hv = fmaxf(acc[mt][ntl][r] + b1c[n], 0.f) * W2c[n];
                    if (isv) v += hv; else p += hv;
                }
            }
            v += __shfl_xor(v, 16, 64); v += __shfl_xor(v, 32, 64);
            p += __shfl_xor(p, 16, 64); p += __shfl_xor(p, 32, 64);
            if (q == 0) {
                int eidx = mt * 16 + i16;
                vpart[w * 128 + eidx] = v;
                ppart[w * 128 + eidx] = p;
            }
        }
    }
    __syncthreads();
    if (t < 128) {
        float v  = vpart[t] + vpart[128 + t] + vpart[256 + t] + vpart[384 + t] + vp_b2[0];
        float pl = ppart[t] + ppart[128 + t] + ppart[256 + t] + ppart[384 + t] + pol_b2[0];
        float prob = 1.0f / (1.0f + expf(-pl));
        int e = e0 + t;
        out[e] = v;
        out[N_EDGES + e] = prob;
        out[2 * N_EDGES + e] = (prob > 0.5f) ? 1.0f : 0.0f;
    }
    if (blockIdx.x == 0 && t == 0) out[3 * N_EDGES] = 0.0f;
}

extern "C" void kernel_launch(void* const* d_in, const int* in_sizes, int n_in,
                              void* d_out, int out_size, void* d_ws, size_t ws_size,
                              hipStream_t stream) {
    const float* x      = (const float*)d_in[0];
    const int*   ei     = (const int*)  d_in[1];
    const float* gf     = (const float*)d_in[2];
    const float* node_W = (const float*)d_in[3];
    const float* node_b = (const float*)d_in[4];
    const float* nbr_W  = (const float*)d_in[5];
    const float* nbr_b  = (const float*)d_in[6];
    const float* gud_W  = (const float*)d_in[7];
    const float* gud_b  = (const float*)d_in[8];
    const float* enc_W  = (const float*)d_in[9];
    const float* enc_b  = (const float*)d_in[10];
    const float* vp_W1  = (const float*)d_in[11];
    const float* vp_b1  = (const float*)d_in[12];
    const float* vp_W2  = (const float*)d_in[13];
    const float* vp_b2  = (const float*)d_in[14];
    const float* pol_W1 = (const float*)d_in[15];
    const float* pol_b1 = (const float*)d_in[16];
    const float* pol_W2 = (const float*)d_in[17];
    const float* pol_b2 = (const float*)d_in[18];
    float* out = (float*)d_out;

    unsigned char* wsb = (unsigned char*)d_ws;
    unsigned short* BTn0 = (unsigned short*)(wsb + 0);
    unsigned short* BTn1 = (unsigned short*)(wsb + 65536);
    unsigned short* BTn2 = (unsigned short*)(wsb + 131072);
    unsigned short* BTg0 = (unsigned short*)(wsb + 196608);
    unsigned short* BTg1 = (unsigned short*)(wsb + 229376);
    unsigned short* BTg2 = (unsigned short*)(wsb + 262144);
    unsigned short* BTw0 = (unsigned short*)(wsb + 294912);
    unsigned short* BTw1 = (unsigned short*)(wsb + 344064);
    unsigned short* BTw2 = (unsigned short*)(wsb + 393216);
    float* cb   = (float*)(wsb + 442368);
    float* b1c  = (float*)(wsb + 442880);
    float* W2c  = (float*)(wsb + 443648);
    int*   flags= (int*)  (wsb + 444416);
    float* Pd   = (float*)(wsb + 444480);
    float* Qd   = Pd + (size_t)N_NODES * 128;

    prep_kernel<<<dim3(128), dim3(256), 0, stream>>>(
        node_W, node_b, nbr_W, nbr_b, gud_W, gud_b, enc_W, enc_b,
        vp_W1, vp_b1, vp_W2, pol_W1, pol_b1, pol_W2,
        BTn0, BTn1, BTn2, BTg0, BTg1, BTg2, BTw0, BTw1, BTw2,
        cb, b1c, W2c, flags);

    node_kernel<<<dim3((N_NODES + 63) / 64), dim3(256), 0, stream>>>(
        x, gf, BTn0, BTn1, BTn2, BTg0, BTg1, BTg2, cb, flags, Pd, Qd);

    edge_kernel<<<dim3(N_EDGES / 128), dim3(256), 0, stream>>>(
        ei, Pd, Qd, BTw0, BTw1, BTw2, b1c, W2c, vp_b2, pol_b2, flags, out);
}